// Round 3
// baseline (209.624 us; speedup 1.0000x reference)
//
#include <hip/hip_runtime.h>
#include <hip/hip_bf16.h>
#include <math.h>

typedef unsigned short u16;
typedef unsigned int u32;
typedef __attribute__((ext_vector_type(4))) float f32x4;
typedef __attribute__((ext_vector_type(8))) short bf16x8;
typedef __attribute__((ext_vector_type(4))) unsigned short us4;
typedef __attribute__((ext_vector_type(8))) unsigned short us8;

#define DI __device__ __forceinline__

DI u16 f2b(float x){ __hip_bfloat16 h = __float2bfloat16(x); return *reinterpret_cast<u16*>(&h); }
DI float b2f(u16 u){ union { float f; u32 i; } v; v.i = ((u32)u) << 16; return v.f; }

// ------------------------------------------------------------------
// 1) weights -> bf16. WB = [Wq;Wk;Wv] (1536x512), WoB = Wo (512x512)
// ------------------------------------------------------------------
__global__ void k_cvt(const float* __restrict__ Wq, const float* __restrict__ Wk,
                      const float* __restrict__ Wv, const float* __restrict__ Wo,
                      u16* __restrict__ WB, u16* __restrict__ WoB){
  int i = blockIdx.x * 256 + threadIdx.x;
  WB[i]          = f2b(Wq[i]);
  WB[262144 + i] = f2b(Wk[i]);
  WB[524288 + i] = f2b(Wv[i]);
  WoB[i]         = f2b(Wo[i]);
}

// ------------------------------------------------------------------
// 2) pooled[b][c] = mean_n x[b][c][n]
// ------------------------------------------------------------------
__global__ __launch_bounds__(256) void k_pooled(const float* __restrict__ x, float* __restrict__ pooled){
  int row  = blockIdx.x * 4 + (threadIdx.x >> 6);
  int lane = threadIdx.x & 63;
  const float4* p = (const float4*)(x + ((size_t)row << 10));
  float4 v0 = p[lane], v1 = p[lane + 64], v2 = p[lane + 128], v3 = p[lane + 192];
  float s = (v0.x + v0.y + v0.z + v0.w) + (v1.x + v1.y + v1.z + v1.w)
          + (v2.x + v2.y + v2.z + v2.w) + (v3.x + v3.y + v3.z + v3.w);
  #pragma unroll
  for (int o = 32; o > 0; o >>= 1) s += __shfl_down(s, o, 64);
  if (lane == 0) pooled[row] = s * (1.0f / 1024.0f);
}

// ------------------------------------------------------------------
// 3) SE
// ------------------------------------------------------------------
__global__ __launch_bounds__(256) void k_se(const float* __restrict__ pooled,
    const float* __restrict__ Wse1, const float* __restrict__ bse1,
    const float* __restrict__ Wse2, const float* __restrict__ bse2,
    float* __restrict__ cw){
  __shared__ float pl[512];
  __shared__ float h1[32];
  int b = blockIdx.x, t = threadIdx.x;
  pl[t] = pooled[b * 512 + t];
  pl[t + 256] = pooled[b * 512 + t + 256];
  __syncthreads();
  if (t < 32){
    float acc = bse1[t];
    const float* w = Wse1 + t * 512;
    for (int c = 0; c < 512; c++) acc = fmaf(pl[c], w[c], acc);
    h1[t] = fmaxf(acc, 0.0f);
  }
  __syncthreads();
  for (int c = t; c < 512; c += 256){
    float acc = bse2[c];
    const float* w = Wse2 + c * 32;
    #pragma unroll
    for (int j = 0; j < 32; j++) acc = fmaf(h1[j], w[j], acc);
    cw[b * 512 + c] = 1.0f / (1.0f + expf(-acc));
  }
}

// ------------------------------------------------------------------
// 4) spatial gate (f32 — mask threshold precision-critical)
// ------------------------------------------------------------------
__global__ __launch_bounds__(256) void k_sp(const float* __restrict__ x,
    const float* __restrict__ Wsp, const float* __restrict__ bsp, float* __restrict__ mbuf){
  __shared__ float wsh[4096];
  __shared__ float part[4][512];
  int t = threadIdx.x;
  for (int i = t; i < 4096; i += 256) wsh[i] = Wsp[i];
  __syncthreads();
  int b = blockIdx.x >> 4, n0 = (blockIdx.x & 15) << 6;
  int px = t & 63, cq = t >> 6;
  const float* xp = x + ((size_t)b << 19) + ((size_t)(cq * 128) << 10) + n0 + px;
  float acc[8] = {0,0,0,0,0,0,0,0};
  for (int c = 0; c < 128; c++){
    float xv = xp[(size_t)c << 10];
    #pragma unroll
    for (int h = 0; h < 8; h++) acc[h] = fmaf(xv, wsh[(h << 9) + cq * 128 + c], acc[h]);
  }
  #pragma unroll
  for (int h = 0; h < 8; h++) part[cq][(h << 6) + px] = acc[h];
  __syncthreads();
  for (int i = t; i < 512; i += 256){
    int h = i >> 6, p = i & 63;
    float s = part[0][i] + part[1][i] + part[2][i] + part[3][i] + bsp[h];
    mbuf[(((size_t)(b * 8 + h)) << 10) + n0 + p] = 1.0f / (1.0f + expf(-s));
  }
}

// ------------------------------------------------------------------
// 5) adaptive pool 7x7, threshold, upsample -> bneg (B,8,N) in {0,-1e9}
// ------------------------------------------------------------------
__global__ void k_mask(const float* __restrict__ mbuf, float* __restrict__ bneg){
  __shared__ float sm[1024];
  __shared__ float mg[49];
  int bh = blockIdx.x, t = threadIdx.x;
  const float* mp = mbuf + ((size_t)bh << 10);
  for (int i = t; i < 1024; i += 64) sm[i] = mp[i];
  __syncthreads();
  if (t < 49){
    int ci = t / 7, cj = t % 7;
    int r0 = (ci * 32) / 7, r1 = ((ci + 1) * 32 + 6) / 7;
    int c0 = (cj * 32) / 7, c1 = ((cj + 1) * 32 + 6) / 7;
    float acc = 0.0f;
    for (int cc = c0; cc < c1; cc++){
      float rs = 0.0f;
      for (int rr = r0; rr < r1; rr++) rs += sm[rr * 32 + cc];
      acc += rs / (float)(r1 - r0);
    }
    float v = acc / (float)(c1 - c0);
    mg[t] = (v > 0.5f) ? 1.0f : 0.0f;
  }
  __syncthreads();
  for (int i = t; i < 1024; i += 64){
    int r = i >> 5, c = i & 31;
    float m = mg[((r * 7) >> 5) * 7 + ((c * 7) >> 5)];
    bneg[((size_t)bh << 10) + i] = (m > 0.5f) ? 0.0f : -1e9f;
  }
}

// ------------------------------------------------------------------
// 6) xf[b][n][c] = bf16( x[b][c][n] * cw[b][c] )
// ------------------------------------------------------------------
__global__ __launch_bounds__(256) void k_xf(const float* __restrict__ x,
    const float* __restrict__ cw, u16* __restrict__ xfB){
  __shared__ float tile[64][65];
  int bid = blockIdx.x;
  int b = bid >> 7, c0 = ((bid >> 4) & 7) << 6, n0 = (bid & 15) << 6;
  int t = threadIdx.x;
  {
    int cl = t >> 2, nc = (t & 3) << 4;
    const float* xp = x + ((size_t)(b * 512 + c0 + cl) << 10) + n0 + nc;
    float cwv = cw[b * 512 + c0 + cl];
    #pragma unroll
    for (int i = 0; i < 16; i += 4){
      float4 v = *(const float4*)(xp + i);
      tile[cl][nc + i + 0] = v.x * cwv;
      tile[cl][nc + i + 1] = v.y * cwv;
      tile[cl][nc + i + 2] = v.z * cwv;
      tile[cl][nc + i + 3] = v.w * cwv;
    }
  }
  __syncthreads();
  {
    int nl = t >> 2, cc = (t & 3) << 4;
    u16* op = xfB + ((size_t)(b * 1024 + n0 + nl) << 9) + c0 + cc;
    us8 o0, o1;
    #pragma unroll
    for (int i = 0; i < 8; i++)  o0[i] = f2b(tile[cc + i][nl]);
    #pragma unroll
    for (int i = 0; i < 8; i++)  o1[i] = f2b(tile[cc + 8 + i][nl]);
    *(us8*)op = o0;
    *(us8*)(op + 8) = o1;
  }
}

// ------------------------------------------------------------------
// 7/9) bf16 MFMA GEMM, BK=64, reg prefetch.
//   Q/K and MODE1 frags use SWAPPED mfma (tokens on lane&15, channels on
//   reg idx) -> packed us4/float4 epilogue stores. V frags unswapped ->
//   transposed+slot-permuted Vt store (packed along tokens).
// ------------------------------------------------------------------
template<int MODE>
__global__ __launch_bounds__(256) void k_gemm(const u16* __restrict__ A, const u16* __restrict__ Bw,
    const float* __restrict__ b0, const float* __restrict__ b1, const float* __restrict__ b2,
    u16* __restrict__ outQ, u16* __restrict__ outK, u16* __restrict__ outV, float* __restrict__ outF){
  __shared__ __align__(16) u16 As[128 * 72];
  __shared__ __align__(16) u16 Bs[128 * 72];
  int m0 = blockIdx.x * 128, n0 = blockIdx.y * 128;
  bool vblk = (MODE == 0) && (n0 >= 1024);
  int t = threadIdx.x, lane = t & 63, w = t >> 6;
  int wr = w >> 1, wc = w & 1;
  int g = lane >> 4, li = lane & 15;
  f32x4 acc[4][4];
  #pragma unroll
  for (int mt = 0; mt < 4; mt++)
    #pragma unroll
    for (int nt = 0; nt < 4; nt++) acc[mt][nt] = (f32x4){0.f, 0.f, 0.f, 0.f};

  int srow = t >> 1, scol = (t & 1) << 5;   // 32 u16 per thread per matrix
  const u16* ap = A  + (size_t)(m0 + srow) * 512 + scol;
  const u16* bp = Bw + (size_t)(n0 + srow) * 512 + scol;

  uint4 pa[4], pb[4];
  #pragma unroll
  for (int j = 0; j < 4; j++){ pa[j] = *(const uint4*)(ap + j * 8); pb[j] = *(const uint4*)(bp + j * 8); }

  for (int k0 = 0; k0 < 512; k0 += 64){
    #pragma unroll
    for (int j = 0; j < 4; j++){
      *(uint4*)&As[srow * 72 + scol + j * 8] = pa[j];
      *(uint4*)&Bs[srow * 72 + scol + j * 8] = pb[j];
    }
    __syncthreads();
    if (k0 < 448){
      #pragma unroll
      for (int j = 0; j < 4; j++){
        pa[j] = *(const uint4*)(ap + k0 + 64 + j * 8);
        pb[j] = *(const uint4*)(bp + k0 + 64 + j * 8);
      }
    }
    #pragma unroll
    for (int kk = 0; kk < 2; kk++){
      bf16x8 afr[4], bfr[4];
      #pragma unroll
      for (int mt = 0; mt < 4; mt++)
        afr[mt] = *(bf16x8*)&As[(wr * 64 + mt * 16 + li) * 72 + kk * 32 + g * 8];
      #pragma unroll
      for (int nt = 0; nt < 4; nt++)
        bfr[nt] = *(bf16x8*)&Bs[(wc * 64 + nt * 16 + li) * 72 + kk * 32 + g * 8];
      if (vblk){
        #pragma unroll
        for (int mt = 0; mt < 4; mt++)
          #pragma unroll
          for (int nt = 0; nt < 4; nt++)
            acc[mt][nt] = __builtin_amdgcn_mfma_f32_16x16x32_bf16(afr[mt], bfr[nt], acc[mt][nt], 0, 0, 0);
      } else {
        #pragma unroll
        for (int mt = 0; mt < 4; mt++)
          #pragma unroll
          for (int nt = 0; nt < 4; nt++)
            acc[mt][nt] = __builtin_amdgcn_mfma_f32_16x16x32_bf16(bfr[nt], afr[mt], acc[mt][nt], 0, 0, 0);
      }
    }
    __syncthreads();
  }

  #pragma unroll
  for (int mt = 0; mt < 4; mt++){
    #pragma unroll
    for (int nt = 0; nt < 4; nt++){
      if (MODE == 0 && vblk){
        // unswapped: row(4g+j)=m, col(li)=o. V -> Vt[bh][d][n'] packed us4
        int o = n0 + wc * 64 + nt * 16 + li;
        int c = o & 511, h = c >> 6, d = c & 63;
        int mb = m0 + wr * 64 + mt * 16 + (g << 2);
        int b = mb >> 10, n = mb & 1023;
        float bias = b2[c];
        int nperm = (n & ~31) + (((n >> 2) & 3) << 3) + (((n >> 4) & 1) << 2);
        us4 pk;
        #pragma unroll
        for (int j = 0; j < 4; j++) pk[j] = f2b(acc[mt][nt][j] + bias);
        *(us4*)&outV[(((size_t)(b * 8 + h)) << 16) + ((size_t)d << 10) + nperm] = pk;
      } else if (MODE == 0){
        // swapped: row(4g+j)=o, col(li)=m. Q/K -> [bh][n][d] packed us4
        int m = m0 + wr * 64 + mt * 16 + li;
        int b = m >> 10, n = m & 1023;
        int obase = n0 + wc * 64 + nt * 16;
        int which = obase >> 9;
        int c = obase & 511, h = c >> 6;
        int dloc = (c & 63) + (g << 2);
        const float* bb = which ? b1 : b0;
        float4 bias4 = *(const float4*)&bb[c + (g << 2)];
        float bk4[4] = {bias4.x, bias4.y, bias4.z, bias4.w};
        u16* base = which ? outK : outQ;
        us4 pk;
        #pragma unroll
        for (int j = 0; j < 4; j++) pk[j] = f2b(acc[mt][nt][j] + bk4[j]);
        *(us4*)&base[(((size_t)(b * 8 + h)) << 16) + ((size_t)n << 6) + dloc] = pk;
      } else {
        // MODE 1 swapped: float4 store
        int m = m0 + wr * 64 + mt * 16 + li;
        int obase = n0 + wc * 64 + nt * 16 + (g << 2);
        float4 bias4 = *(const float4*)&b0[obase];
        float4 vo = { acc[mt][nt][0] + bias4.x, acc[mt][nt][1] + bias4.y,
                      acc[mt][nt][2] + bias4.z, acc[mt][nt][3] + bias4.w };
        *(float4*)&outF[(size_t)m * 512 + obase] = vo;
      }
    }
  }
}

// ------------------------------------------------------------------
// 8) flash attention, split-KV 8-wave: waves {w,w+4} share 16 q-rows,
//    process even/odd KV tiles into LDS set 0/1, merge at end.
//    XCD-swizzled blockIdx so each bh stays on one XCD.
// ------------------------------------------------------------------
__global__ __launch_bounds__(512) void k_flash(const u16* __restrict__ Q, const u16* __restrict__ K,
    const u16* __restrict__ Vt, const float* __restrict__ bneg, u16* __restrict__ attnB){
  __shared__ __align__(16) u16 Ks[2][64 * 72];
  __shared__ __align__(16) u16 Vts[2][64 * 72];
  __shared__ float mks[2][64];
  int hw = blockIdx.x;
  int bid = ((hw & 7) << 7) + (hw >> 3);        // bijective: 1024 % 8 == 0
  int bh = bid >> 4, q0 = (bid & 15) << 6;
  int t = threadIdx.x, lane = t & 63, w = t >> 6;
  int qw = w & 3, half = w >> 2;
  int g = lane >> 4, li = lane & 15;

  const u16* Kp = K  + ((size_t)bh << 16);
  const u16* Vp = Vt + ((size_t)bh << 16);
  const float* bp = bneg + ((size_t)bh << 10);

  bf16x8 qfr0, qfr1;
  {
    const u16* qrow = Q + ((size_t)bh << 16) + ((size_t)(q0 + qw * 16 + li) << 6);
    qfr0 = *(const bf16x8*)(qrow + g * 8);
    qfr1 = *(const bf16x8*)(qrow + 32 + g * 8);
  }
  float bnq = bp[q0 + qw * 16 + li];

  f32x4 oacc[4];
  #pragma unroll
  for (int dt = 0; dt < 4; dt++) oacc[dt] = (f32x4){0.f, 0.f, 0.f, 0.f};
  float mrun = -INFINITY, lrun = 0.0f;

  // staging: 256-thread group 'sset' stages LDS set 'sset' (tiles 2i+sset)
  int tl = t & 255, sset = t >> 8;
  int sr = tl >> 2, sc = (tl & 3) << 4;
  const u16* kg = Kp + (sr << 6) + sc + (sset << 12);
  const u16* vg = Vp + (sr << 10) + sc + (sset << 6);
  uint4 kr0 = *(const uint4*)kg,       kr1 = *(const uint4*)(kg + 8);
  uint4 vr0 = *(const uint4*)vg,       vr1 = *(const uint4*)(vg + 8);
  float mr = (tl < 64) ? bp[(sset << 6) + tl] : 0.0f;

  for (int i = 0; i < 8; i++){
    __syncthreads();
    *(uint4*)&Ks[sset][sr * 72 + sc]      = kr0;
    *(uint4*)&Ks[sset][sr * 72 + sc + 8]  = kr1;
    *(uint4*)&Vts[sset][sr * 72 + sc]     = vr0;
    *(uint4*)&Vts[sset][sr * 72 + sc + 8] = vr1;
    if (tl < 64) mks[sset][tl] = mr;
    if (i < 7){
      int off = (i + 1) << 1;
      kr0 = *(const uint4*)(kg + off * 4096);
      kr1 = *(const uint4*)(kg + off * 4096 + 8);
      vr0 = *(const uint4*)(vg + off * 64);
      vr1 = *(const uint4*)(vg + off * 64 + 8);
      if (tl < 64) mr = bp[((off + sset) << 6) + tl];
    }
    __syncthreads();

    // S^T = K Q^T on set 'half'
    f32x4 sacc[4];
    #pragma unroll
    for (int mt = 0; mt < 4; mt++) sacc[mt] = (f32x4){0.f, 0.f, 0.f, 0.f};
    #pragma unroll
    for (int mt = 0; mt < 4; mt++){
      bf16x8 kfr0 = *(bf16x8*)&Ks[half][(mt * 16 + li) * 72 + g * 8];
      bf16x8 kfr1 = *(bf16x8*)&Ks[half][(mt * 16 + li) * 72 + 32 + g * 8];
      sacc[mt] = __builtin_amdgcn_mfma_f32_16x16x32_bf16(kfr0, qfr0, sacc[mt], 0, 0, 0);
      sacc[mt] = __builtin_amdgcn_mfma_f32_16x16x32_bf16(kfr1, qfr1, sacc[mt], 0, 0, 0);
    }

    float tmax = -INFINITY;
    #pragma unroll
    for (int mt = 0; mt < 4; mt++){
      float4 bk = *(const float4*)&mks[half][mt * 16 + g * 4];
      float bkk[4] = {bk.x, bk.y, bk.z, bk.w};
      #pragma unroll
      for (int j = 0; j < 4; j++){
        float s = sacc[mt][j] * 0.125f + fminf(bkk[j], bnq);
        sacc[mt][j] = s;
        tmax = fmaxf(tmax, s);
      }
    }
    tmax = fmaxf(tmax, __shfl_xor(tmax, 16, 64));
    tmax = fmaxf(tmax, __shfl_xor(tmax, 32, 64));

    // defer-max (T13): rescale only if max grew past threshold
    if (!__all(tmax <= mrun + 8.0f)){
      float mnew = fmaxf(mrun, tmax);
      float scl = __expf(mrun - mnew);
      mrun = mnew;
      lrun *= scl;
      #pragma unroll
      for (int dt = 0; dt < 4; dt++)
        #pragma unroll
        for (int j = 0; j < 4; j++) oacc[dt][j] *= scl;
    }

    float rsum = 0.0f;
    #pragma unroll
    for (int mt = 0; mt < 4; mt++)
      #pragma unroll
      for (int j = 0; j < 4; j++){
        float p = __expf(sacc[mt][j] - mrun);
        sacc[mt][j] = p;
        rsum += p;
      }
    rsum += __shfl_xor(rsum, 16, 64);
    rsum += __shfl_xor(rsum, 32, 64);
    lrun += rsum;

    bf16x8 pfr0, pfr1;
    #pragma unroll
    for (int e = 0; e < 4; e++){
      pfr0[e]     = (short)f2b(sacc[0][e]);
      pfr0[4 + e] = (short)f2b(sacc[1][e]);
      pfr1[e]     = (short)f2b(sacc[2][e]);
      pfr1[4 + e] = (short)f2b(sacc[3][e]);
    }
    #pragma unroll
    for (int dt = 0; dt < 4; dt++){
      bf16x8 vfr0 = *(bf16x8*)&Vts[half][(dt * 16 + li) * 72 + g * 8];
      bf16x8 vfr1 = *(bf16x8*)&Vts[half][(dt * 16 + li) * 72 + 32 + g * 8];
      oacc[dt] = __builtin_amdgcn_mfma_f32_16x16x32_bf16(vfr0, pfr0, oacc[dt], 0, 0, 0);
      oacc[dt] = __builtin_amdgcn_mfma_f32_16x16x32_bf16(vfr1, pfr1, oacc[dt], 0, 0, 0);
    }
  }

  // merge halves: waves 4-7 publish (m,l,O) via LDS (alias over Ks)
  __syncthreads();
  float* pm = (float*)&Ks[0][0];      // 256 f
  float* pl = pm + 256;               // 256 f
  float* po = pl + 256;               // 4096 f  (total 18432 B = sizeof Ks)
  int slot = qw * 64 + lane;
  if (half == 1){
    pm[slot] = mrun;
    pl[slot] = lrun;
    #pragma unroll
    for (int dt = 0; dt < 4; dt++) *(f32x4*)&po[slot * 16 + dt * 4] = oacc[dt];
  }
  __syncthreads();
  if (half == 0){
    float mb = pm[slot], lb = pl[slot];
    float mm = fmaxf(mrun, mb);
    float ea = __expf(mrun - mm), eb = __expf(mb - mm);
    float linv = 1.0f / (lrun * ea + lb * eb);
    int b = bh >> 3, h = bh & 7;
    u16* op = attnB + (((size_t)(b * 1024 + q0 + qw * 16 + li)) << 9) + h * 64 + g * 4;
    #pragma unroll
    for (int dt = 0; dt < 4; dt++){
      f32x4 ob = *(f32x4*)&po[slot * 16 + dt * 4];
      us4 pk;
      #pragma unroll
      for (int j = 0; j < 4; j++) pk[j] = f2b((oacc[dt][j] * ea + ob[j] * eb) * linv);
      *(us4*)(op + dt * 16) = pk;
    }
  }
}

// ------------------------------------------------------------------
// 10) LN over C + transpose to (B,C,N)
// ------------------------------------------------------------------
__global__ __launch_bounds__(256) void k_ln(const u16* __restrict__ xfB, const float* __restrict__ attnO,
    const float* __restrict__ gamma, const float* __restrict__ beta, float* __restrict__ out){
  __shared__ float mu_s[64], rs_s[64];
  __shared__ float tile[64][65];
  int b = blockIdx.x >> 4, n0 = (blockIdx.x & 15) << 6;
  int t = threadIdx.x, w = t >> 6, lane = t & 63;

  for (int r = w * 16; r < w * 16 + 16; r++){
    size_t rb = ((size_t)(b * 1024 + n0 + r)) << 9;
    const float* ap = attnO + rb + lane * 8;
    const u16*  xp = xfB + rb + lane * 8;
    float4 a0 = *(const float4*)ap;
    float4 a1 = *(const float4*)(ap + 4);
    union { uint4 v; u16 u[8]; } xv; xv.v = *(const uint4*)xp;
    float v0 = a0.x + b2f(xv.u[0]), v1 = a0.y + b2f(xv.u[1]);
    float v2 = a0.z + b2f(xv.u[2]), v3 = a0.w + b2f(xv.u[3]);
    float v4 = a1.x + b2f(xv.u[4]), v5 = a1.y + b2f(xv.u[5]);
    float v6 = a1.z + b2f(xv.u[6]), v7 = a1.w + b2f(xv.u[7]);
    float s  = v0 + v1 + v2 + v3 + v4 + v5 + v6 + v7;
    float s2 = v0*v0 + v1*v1 + v2*v2 + v3*v3 + v4*v4 + v5*v5 + v6*v6 + v7*v7;
    #pragma unroll
    for (int o = 32; o > 0; o >>= 1){ s += __shfl_xor(s, o, 64); s2 += __shfl_xor(s2, o, 64); }
    if (lane == 0){
      float mu = s * (1.0f / 512.0f);
      float var = s2 * (1.0f / 512.0f) - mu * mu;
      mu_s[r] = mu;
      rs_s[r] = 1.0f / sqrtf(var + 1e-5f);
    }
  }
  __syncthreads();

  for (int ch = 0; ch < 8; ch++){
    int c0 = ch * 64;
    {
      int r = t >> 2, cp = (t & 3) << 4;
      size_t rb = (((size_t)(b * 1024 + n0 + r)) << 9) + c0 + cp;
      float mu = mu_s[r], rstd = rs_s[r];
      #pragma unroll
      for (int i2 = 0; i2 < 2; i2++){
        float4 a0 = *(const float4*)(attnO + rb + i2 * 8);
        float4 a1 = *(const float4*)(attnO + rb + i2 * 8 + 4);
        union { uint4 v; u16 u[8]; } xv; xv.v = *(const uint4*)(xfB + rb + i2 * 8);
        float vv[8] = { a0.x + b2f(xv.u[0]), a0.y + b2f(xv.u[1]), a0.z + b2f(xv.u[2]), a0.w + b2f(xv.u[3]),
                        a1.x + b2f(xv.u[4]), a1.y + b2f(xv.u[5]), a1.z + b2f(xv.u[6]), a1.w + b2f(xv.u[7]) };
        #pragma unroll
        for (int i = 0; i < 8; i++){
          int c = c0 + cp + i2 * 8 + i;
          tile[r][cp + i2 * 8 + i] = (vv[i] - mu) * rstd * gamma[c] + beta[c];
        }
      }
    }
    __syncthreads();
    {
      int cl = t >> 2, np_ = (t & 3) << 4;
      float* op = out + (((size_t)(b * 512 + c0 + cl)) << 10) + n0 + np_;
      #pragma unroll
      for (int i = 0; i < 16; i += 4){
        float4 vo = { tile[np_ + i][cl], tile[np_ + i + 1][cl], tile[np_ + i + 2][cl], tile[np_ + i + 3][cl] };
        *(float4*)(op + i) = vo;
      }
    }
    __syncthreads();
  }
}

// ------------------------------------------------------------------
extern "C" void kernel_launch(void* const* d_in, const int* in_sizes, int n_in,
                              void* d_out, int out_size, void* d_ws, size_t ws_size,
                              hipStream_t stream){
  (void)in_sizes; (void)n_in; (void)out_size; (void)ws_size;
  const float* x    = (const float*)d_in[0];
  const float* Wq   = (const float*)d_in[1];
  const float* bq   = (const float*)d_in[2];
  const float* Wk   = (const float*)d_in[3];
  const float* bk   = (const float*)d_in[4];
  const float* Wv   = (const float*)d_in[5];
  const float* bv   = (const float*)d_in[6];
  const float* Wo   = (const float*)d_in[7];
  const float* bo   = (const float*)d_in[8];
  const float* Wsp  = (const float*)d_in[9];
  const float* bsp  = (const float*)d_in[10];
  const float* Wse1 = (const float*)d_in[11];
  const float* bse1 = (const float*)d_in[12];
  const float* Wse2 = (const float*)d_in[13];
  const float* bse2 = (const float*)d_in[14];
  const float* gamma= (const float*)d_in[15];
  const float* beta = (const float*)d_in[16];
  float* out = (float*)d_out;

  char* ws = (char*)d_ws;
  size_t off = 0;
  auto alloc = [&](size_t bytes) -> void* {
    void* p = ws + off;
    off += (bytes + 255) & ~(size_t)255;
    return p;
  };
  u16*   WB     = (u16*)  alloc(1536 * 512 * 2);
  u16*   WoB    = (u16*)  alloc(512 * 512 * 2);
  float* pooled = (float*)alloc(4096 * 4);
  float* cw     = (float*)alloc(4096 * 4);
  float* mbuf   = (float*)alloc(65536 * 4);
  float* bneg   = (float*)alloc(65536 * 4);
  u16*   xfB    = (u16*)  alloc((size_t)8192 * 512 * 2);
  u16*   Qb     = (u16*)  alloc(8388608);
  u16*   Kb     = (u16*)  alloc(8388608);
  u16*   VtG    = (u16*)  alloc(8388608);
  u16*   attnB  = (u16*)  alloc(8388608);
  float* attnO  = (float*)Qb;   // alias Q+K after flash

  k_cvt   <<<dim3(1024), dim3(256), 0, stream>>>(Wq, Wk, Wv, Wo, WB, WoB);
  k_pooled<<<dim3(1024), dim3(256), 0, stream>>>(x, pooled);
  k_se    <<<dim3(8),    dim3(256), 0, stream>>>(pooled, Wse1, bse1, Wse2, bse2, cw);
  k_sp    <<<dim3(128),  dim3(256), 0, stream>>>(x, Wsp, bsp, mbuf);
  k_mask  <<<dim3(64),   dim3(64),  0, stream>>>(mbuf, bneg);
  k_xf    <<<dim3(1024), dim3(256), 0, stream>>>(x, cw, xfB);
  k_gemm<0><<<dim3(64, 12), dim3(256), 0, stream>>>(xfB, WB, bq, bk, bv, Qb, Kb, VtG, (float*)nullptr);
  k_flash <<<dim3(1024), dim3(512), 0, stream>>>(Qb, Kb, VtG, bneg, attnB);
  k_gemm<1><<<dim3(64, 4), dim3(256), 0, stream>>>(attnB, WoB, bo, bo, bo, nullptr, nullptr, nullptr, attnO);
  k_ln    <<<dim3(128),  dim3(256), 0, stream>>>(xfB, attnO, gamma, beta, out);
}

// Round 4
// 209.189 us; speedup vs baseline: 1.0021x; 1.0021x over previous
//
#include <hip/hip_runtime.h>
#include <hip/hip_bf16.h>
#include <math.h>

typedef unsigned short u16;
typedef unsigned int u32;
typedef __attribute__((ext_vector_type(4))) float f32x4;
typedef __attribute__((ext_vector_type(8))) short bf16x8;
typedef __attribute__((ext_vector_type(4))) unsigned short us4;
typedef __attribute__((ext_vector_type(8))) unsigned short us8;

#define DI __device__ __forceinline__

DI u16 f2b(float x){ __hip_bfloat16 h = __float2bfloat16(x); return *reinterpret_cast<u16*>(&h); }
DI float b2f(u16 u){ union { float f; u32 i; } v; v.i = ((u32)u) << 16; return v.f; }

// ------------------------------------------------------------------
// 1) weights -> bf16. WB = [Wq;Wk;Wv] (1536x512), WoB = Wo (512x512)
// ------------------------------------------------------------------
__global__ void k_cvt(const float* __restrict__ Wq, const float* __restrict__ Wk,
                      const float* __restrict__ Wv, const float* __restrict__ Wo,
                      u16* __restrict__ WB, u16* __restrict__ WoB){
  int i = blockIdx.x * 256 + threadIdx.x;
  WB[i]          = f2b(Wq[i]);
  WB[262144 + i] = f2b(Wk[i]);
  WB[524288 + i] = f2b(Wv[i]);
  WoB[i]         = f2b(Wo[i]);
}

// ------------------------------------------------------------------
// 2) pooled[b][c] = mean_n x[b][c][n]
// ------------------------------------------------------------------
__global__ __launch_bounds__(256) void k_pooled(const float* __restrict__ x, float* __restrict__ pooled){
  int row  = blockIdx.x * 4 + (threadIdx.x >> 6);
  int lane = threadIdx.x & 63;
  const float4* p = (const float4*)(x + ((size_t)row << 10));
  float4 v0 = p[lane], v1 = p[lane + 64], v2 = p[lane + 128], v3 = p[lane + 192];
  float s = (v0.x + v0.y + v0.z + v0.w) + (v1.x + v1.y + v1.z + v1.w)
          + (v2.x + v2.y + v2.z + v2.w) + (v3.x + v3.y + v3.z + v3.w);
  #pragma unroll
  for (int o = 32; o > 0; o >>= 1) s += __shfl_down(s, o, 64);
  if (lane == 0) pooled[row] = s * (1.0f / 1024.0f);
}

// ------------------------------------------------------------------
// 3) SE
// ------------------------------------------------------------------
__global__ __launch_bounds__(256) void k_se(const float* __restrict__ pooled,
    const float* __restrict__ Wse1, const float* __restrict__ bse1,
    const float* __restrict__ Wse2, const float* __restrict__ bse2,
    float* __restrict__ cw){
  __shared__ float pl[512];
  __shared__ float h1[32];
  int b = blockIdx.x, t = threadIdx.x;
  pl[t] = pooled[b * 512 + t];
  pl[t + 256] = pooled[b * 512 + t + 256];
  __syncthreads();
  if (t < 32){
    float acc = bse1[t];
    const float* w = Wse1 + t * 512;
    for (int c = 0; c < 512; c++) acc = fmaf(pl[c], w[c], acc);
    h1[t] = fmaxf(acc, 0.0f);
  }
  __syncthreads();
  for (int c = t; c < 512; c += 256){
    float acc = bse2[c];
    const float* w = Wse2 + c * 32;
    #pragma unroll
    for (int j = 0; j < 32; j++) acc = fmaf(h1[j], w[j], acc);
    cw[b * 512 + c] = 1.0f / (1.0f + expf(-acc));
  }
}

// ------------------------------------------------------------------
// 4) spatial gate (f32 — mask threshold precision-critical)
// ------------------------------------------------------------------
__global__ __launch_bounds__(256) void k_sp(const float* __restrict__ x,
    const float* __restrict__ Wsp, const float* __restrict__ bsp, float* __restrict__ mbuf){
  __shared__ float wsh[4096];
  __shared__ float part[4][512];
  int t = threadIdx.x;
  for (int i = t; i < 4096; i += 256) wsh[i] = Wsp[i];
  __syncthreads();
  int b = blockIdx.x >> 4, n0 = (blockIdx.x & 15) << 6;
  int px = t & 63, cq = t >> 6;
  const float* xp = x + ((size_t)b << 19) + ((size_t)(cq * 128) << 10) + n0 + px;
  float acc[8] = {0,0,0,0,0,0,0,0};
  for (int c = 0; c < 128; c++){
    float xv = xp[(size_t)c << 10];
    #pragma unroll
    for (int h = 0; h < 8; h++) acc[h] = fmaf(xv, wsh[(h << 9) + cq * 128 + c], acc[h]);
  }
  #pragma unroll
  for (int h = 0; h < 8; h++) part[cq][(h << 6) + px] = acc[h];
  __syncthreads();
  for (int i = t; i < 512; i += 256){
    int h = i >> 6, p = i & 63;
    float s = part[0][i] + part[1][i] + part[2][i] + part[3][i] + bsp[h];
    mbuf[(((size_t)(b * 8 + h)) << 10) + n0 + p] = 1.0f / (1.0f + expf(-s));
  }
}

// ------------------------------------------------------------------
// 5) adaptive pool 7x7, threshold, upsample -> bneg (B,8,N) in {0,-1e9}
// ------------------------------------------------------------------
__global__ void k_mask(const float* __restrict__ mbuf, float* __restrict__ bneg){
  __shared__ float sm[1024];
  __shared__ float mg[49];
  int bh = blockIdx.x, t = threadIdx.x;
  const float* mp = mbuf + ((size_t)bh << 10);
  for (int i = t; i < 1024; i += 64) sm[i] = mp[i];
  __syncthreads();
  if (t < 49){
    int ci = t / 7, cj = t % 7;
    int r0 = (ci * 32) / 7, r1 = ((ci + 1) * 32 + 6) / 7;
    int c0 = (cj * 32) / 7, c1 = ((cj + 1) * 32 + 6) / 7;
    float acc = 0.0f;
    for (int cc = c0; cc < c1; cc++){
      float rs = 0.0f;
      for (int rr = r0; rr < r1; rr++) rs += sm[rr * 32 + cc];
      acc += rs / (float)(r1 - r0);
    }
    float v = acc / (float)(c1 - c0);
    mg[t] = (v > 0.5f) ? 1.0f : 0.0f;
  }
  __syncthreads();
  for (int i = t; i < 1024; i += 64){
    int r = i >> 5, c = i & 31;
    float m = mg[((r * 7) >> 5) * 7 + ((c * 7) >> 5)];
    bneg[((size_t)bh << 10) + i] = (m > 0.5f) ? 0.0f : -1e9f;
  }
}

// ------------------------------------------------------------------
// 6) xf[b][n][c] = bf16( x[b][c][n] * cw[b][c] )
// ------------------------------------------------------------------
__global__ __launch_bounds__(256) void k_xf(const float* __restrict__ x,
    const float* __restrict__ cw, u16* __restrict__ xfB){
  __shared__ float tile[64][65];
  int bid = blockIdx.x;
  int b = bid >> 7, c0 = ((bid >> 4) & 7) << 6, n0 = (bid & 15) << 6;
  int t = threadIdx.x;
  {
    int cl = t >> 2, nc = (t & 3) << 4;
    const float* xp = x + ((size_t)(b * 512 + c0 + cl) << 10) + n0 + nc;
    float cwv = cw[b * 512 + c0 + cl];
    #pragma unroll
    for (int i = 0; i < 16; i += 4){
      float4 v = *(const float4*)(xp + i);
      tile[cl][nc + i + 0] = v.x * cwv;
      tile[cl][nc + i + 1] = v.y * cwv;
      tile[cl][nc + i + 2] = v.z * cwv;
      tile[cl][nc + i + 3] = v.w * cwv;
    }
  }
  __syncthreads();
  {
    int nl = t >> 2, cc = (t & 3) << 4;
    u16* op = xfB + ((size_t)(b * 1024 + n0 + nl) << 9) + c0 + cc;
    us8 o0, o1;
    #pragma unroll
    for (int i = 0; i < 8; i++)  o0[i] = f2b(tile[cc + i][nl]);
    #pragma unroll
    for (int i = 0; i < 8; i++)  o1[i] = f2b(tile[cc + 8 + i][nl]);
    *(us8*)op = o0;
    *(us8*)(op + 8) = o1;
  }
}

// ------------------------------------------------------------------
// 7/9) bf16 MFMA GEMM, BK=64, reg prefetch.
//   Q/K and MODE1 frags use SWAPPED mfma (tokens on lane&15, channels on
//   reg idx) -> packed us4/float4 epilogue stores. V frags unswapped ->
//   transposed+slot-permuted Vt store (packed along tokens).
// ------------------------------------------------------------------
template<int MODE>
__global__ __launch_bounds__(256) void k_gemm(const u16* __restrict__ A, const u16* __restrict__ Bw,
    const float* __restrict__ b0, const float* __restrict__ b1, const float* __restrict__ b2,
    u16* __restrict__ outQ, u16* __restrict__ outK, u16* __restrict__ outV, float* __restrict__ outF){
  __shared__ __align__(16) u16 As[128 * 72];
  __shared__ __align__(16) u16 Bs[128 * 72];
  int m0 = blockIdx.x * 128, n0 = blockIdx.y * 128;
  bool vblk = (MODE == 0) && (n0 >= 1024);
  int t = threadIdx.x, lane = t & 63, w = t >> 6;
  int wr = w >> 1, wc = w & 1;
  int g = lane >> 4, li = lane & 15;
  f32x4 acc[4][4];
  #pragma unroll
  for (int mt = 0; mt < 4; mt++)
    #pragma unroll
    for (int nt = 0; nt < 4; nt++) acc[mt][nt] = (f32x4){0.f, 0.f, 0.f, 0.f};

  int srow = t >> 1, scol = (t & 1) << 5;   // 32 u16 per thread per matrix
  const u16* ap = A  + (size_t)(m0 + srow) * 512 + scol;
  const u16* bp = Bw + (size_t)(n0 + srow) * 512 + scol;

  uint4 pa[4], pb[4];
  #pragma unroll
  for (int j = 0; j < 4; j++){ pa[j] = *(const uint4*)(ap + j * 8); pb[j] = *(const uint4*)(bp + j * 8); }

  for (int k0 = 0; k0 < 512; k0 += 64){
    #pragma unroll
    for (int j = 0; j < 4; j++){
      *(uint4*)&As[srow * 72 + scol + j * 8] = pa[j];
      *(uint4*)&Bs[srow * 72 + scol + j * 8] = pb[j];
    }
    __syncthreads();
    if (k0 < 448){
      #pragma unroll
      for (int j = 0; j < 4; j++){
        pa[j] = *(const uint4*)(ap + k0 + 64 + j * 8);
        pb[j] = *(const uint4*)(bp + k0 + 64 + j * 8);
      }
    }
    #pragma unroll
    for (int kk = 0; kk < 2; kk++){
      bf16x8 afr[4], bfr[4];
      #pragma unroll
      for (int mt = 0; mt < 4; mt++)
        afr[mt] = *(bf16x8*)&As[(wr * 64 + mt * 16 + li) * 72 + kk * 32 + g * 8];
      #pragma unroll
      for (int nt = 0; nt < 4; nt++)
        bfr[nt] = *(bf16x8*)&Bs[(wc * 64 + nt * 16 + li) * 72 + kk * 32 + g * 8];
      if (vblk){
        #pragma unroll
        for (int mt = 0; mt < 4; mt++)
          #pragma unroll
          for (int nt = 0; nt < 4; nt++)
            acc[mt][nt] = __builtin_amdgcn_mfma_f32_16x16x32_bf16(afr[mt], bfr[nt], acc[mt][nt], 0, 0, 0);
      } else {
        #pragma unroll
        for (int mt = 0; mt < 4; mt++)
          #pragma unroll
          for (int nt = 0; nt < 4; nt++)
            acc[mt][nt] = __builtin_amdgcn_mfma_f32_16x16x32_bf16(bfr[nt], afr[mt], acc[mt][nt], 0, 0, 0);
      }
    }
    __syncthreads();
  }

  #pragma unroll
  for (int mt = 0; mt < 4; mt++){
    #pragma unroll
    for (int nt = 0; nt < 4; nt++){
      if (MODE == 0 && vblk){
        // unswapped: row(4g+j)=m, col(li)=o. V -> Vt[bh][d][n'] packed us4
        int o = n0 + wc * 64 + nt * 16 + li;
        int c = o & 511, h = c >> 6, d = c & 63;
        int mb = m0 + wr * 64 + mt * 16 + (g << 2);
        int b = mb >> 10, n = mb & 1023;
        float bias = b2[c];
        int nperm = (n & ~31) + (((n >> 2) & 3) << 3) + (((n >> 4) & 1) << 2);
        us4 pk;
        #pragma unroll
        for (int j = 0; j < 4; j++) pk[j] = f2b(acc[mt][nt][j] + bias);
        *(us4*)&outV[(((size_t)(b * 8 + h)) << 16) + ((size_t)d << 10) + nperm] = pk;
      } else if (MODE == 0){
        // swapped: row(4g+j)=o, col(li)=m. Q/K -> [bh][n][d] packed us4
        int m = m0 + wr * 64 + mt * 16 + li;
        int b = m >> 10, n = m & 1023;
        int obase = n0 + wc * 64 + nt * 16;
        int which = obase >> 9;
        int c = obase & 511, h = c >> 6;
        int dloc = (c & 63) + (g << 2);
        const float* bb = which ? b1 : b0;
        float4 bias4 = *(const float4*)&bb[c + (g << 2)];
        float bk4[4] = {bias4.x, bias4.y, bias4.z, bias4.w};
        u16* base = which ? outK : outQ;
        us4 pk;
        #pragma unroll
        for (int j = 0; j < 4; j++) pk[j] = f2b(acc[mt][nt][j] + bk4[j]);
        *(us4*)&base[(((size_t)(b * 8 + h)) << 16) + ((size_t)n << 6) + dloc] = pk;
      } else {
        // MODE 1 swapped: float4 store
        int m = m0 + wr * 64 + mt * 16 + li;
        int obase = n0 + wc * 64 + nt * 16 + (g << 2);
        float4 bias4 = *(const float4*)&b0[obase];
        float4 vo = { acc[mt][nt][0] + bias4.x, acc[mt][nt][1] + bias4.y,
                      acc[mt][nt][2] + bias4.z, acc[mt][nt][3] + bias4.w };
        *(float4*)&outF[(size_t)m * 512 + obase] = vo;
      }
    }
  }
}

// ------------------------------------------------------------------
// 8) flash attention, split-KV 8-wave: waves {w,w+4} share 16 q-rows,
//    process even/odd KV tiles into LDS set 0/1, merge at end.
//    XCD-swizzled blockIdx so each bh stays on one XCD.
// ------------------------------------------------------------------
__global__ __launch_bounds__(512) void k_flash(const u16* __restrict__ Q, const u16* __restrict__ K,
    const u16* __restrict__ Vt, const float* __restrict__ bneg, u16* __restrict__ attnB){
  __shared__ __align__(16) u16 Ks[2][64 * 72];
  __shared__ __align__(16) u16 Vts[2][64 * 72];
  __shared__ float mks[2][64];
  int hw = blockIdx.x;
  int bid = ((hw & 7) << 7) + (hw >> 3);        // bijective: 1024 % 8 == 0
  int bh = bid >> 4, q0 = (bid & 15) << 6;
  int t = threadIdx.x, lane = t & 63, w = t >> 6;
  int qw = w & 3, half = w >> 2;
  int g = lane >> 4, li = lane & 15;

  const u16* Kp = K  + ((size_t)bh << 16);
  const u16* Vp = Vt + ((size_t)bh << 16);
  const float* bp = bneg + ((size_t)bh << 10);

  bf16x8 qfr0, qfr1;
  {
    const u16* qrow = Q + ((size_t)bh << 16) + ((size_t)(q0 + qw * 16 + li) << 6);
    qfr0 = *(const bf16x8*)(qrow + g * 8);
    qfr1 = *(const bf16x8*)(qrow + 32 + g * 8);
  }
  float bnq = bp[q0 + qw * 16 + li];

  f32x4 oacc[4];
  #pragma unroll
  for (int dt = 0; dt < 4; dt++) oacc[dt] = (f32x4){0.f, 0.f, 0.f, 0.f};
  float mrun = -INFINITY, lrun = 0.0f;

  // staging: 256-thread group 'sset' stages LDS set 'sset' (tiles 2i+sset)
  int tl = t & 255, sset = t >> 8;
  int sr = tl >> 2, sc = (tl & 3) << 4;
  const u16* kg = Kp + (sr << 6) + sc + (sset << 12);
  const u16* vg = Vp + (sr << 10) + sc + (sset << 6);
  uint4 kr0 = *(const uint4*)kg,       kr1 = *(const uint4*)(kg + 8);
  uint4 vr0 = *(const uint4*)vg,       vr1 = *(const uint4*)(vg + 8);
  float mr = (tl < 64) ? bp[(sset << 6) + tl] : 0.0f;

  for (int i = 0; i < 8; i++){
    __syncthreads();
    *(uint4*)&Ks[sset][sr * 72 + sc]      = kr0;
    *(uint4*)&Ks[sset][sr * 72 + sc + 8]  = kr1;
    *(uint4*)&Vts[sset][sr * 72 + sc]     = vr0;
    *(uint4*)&Vts[sset][sr * 72 + sc + 8] = vr1;
    if (tl < 64) mks[sset][tl] = mr;
    if (i < 7){
      int off = (i + 1) << 1;
      kr0 = *(const uint4*)(kg + off * 4096);
      kr1 = *(const uint4*)(kg + off * 4096 + 8);
      vr0 = *(const uint4*)(vg + off * 64);
      vr1 = *(const uint4*)(vg + off * 64 + 8);
      if (tl < 64) mr = bp[((off + sset) << 6) + tl];
    }
    __syncthreads();

    // S^T = K Q^T on set 'half'
    f32x4 sacc[4];
    #pragma unroll
    for (int mt = 0; mt < 4; mt++) sacc[mt] = (f32x4){0.f, 0.f, 0.f, 0.f};
    #pragma unroll
    for (int mt = 0; mt < 4; mt++){
      bf16x8 kfr0 = *(bf16x8*)&Ks[half][(mt * 16 + li) * 72 + g * 8];
      bf16x8 kfr1 = *(bf16x8*)&Ks[half][(mt * 16 + li) * 72 + 32 + g * 8];
      sacc[mt] = __builtin_amdgcn_mfma_f32_16x16x32_bf16(kfr0, qfr0, sacc[mt], 0, 0, 0);
      sacc[mt] = __builtin_amdgcn_mfma_f32_16x16x32_bf16(kfr1, qfr1, sacc[mt], 0, 0, 0);
    }

    float tmax = -INFINITY;
    #pragma unroll
    for (int mt = 0; mt < 4; mt++){
      float4 bk = *(const float4*)&mks[half][mt * 16 + g * 4];
      float bkk[4] = {bk.x, bk.y, bk.z, bk.w};
      #pragma unroll
      for (int j = 0; j < 4; j++){
        float s = sacc[mt][j] * 0.125f + fminf(bkk[j], bnq);
        sacc[mt][j] = s;
        tmax = fmaxf(tmax, s);
      }
    }
    tmax = fmaxf(tmax, __shfl_xor(tmax, 16, 64));
    tmax = fmaxf(tmax, __shfl_xor(tmax, 32, 64));

    // defer-max (T13): rescale only if max grew past threshold
    if (!__all(tmax <= mrun + 8.0f)){
      float mnew = fmaxf(mrun, tmax);
      float scl = __expf(mrun - mnew);
      mrun = mnew;
      lrun *= scl;
      #pragma unroll
      for (int dt = 0; dt < 4; dt++)
        #pragma unroll
        for (int j = 0; j < 4; j++) oacc[dt][j] *= scl;
    }

    float rsum = 0.0f;
    #pragma unroll
    for (int mt = 0; mt < 4; mt++)
      #pragma unroll
      for (int j = 0; j < 4; j++){
        float p = __expf(sacc[mt][j] - mrun);
        sacc[mt][j] = p;
        rsum += p;
      }
    rsum += __shfl_xor(rsum, 16, 64);
    rsum += __shfl_xor(rsum, 32, 64);
    lrun += rsum;

    bf16x8 pfr0, pfr1;
    #pragma unroll
    for (int e = 0; e < 4; e++){
      pfr0[e]     = (short)f2b(sacc[0][e]);
      pfr0[4 + e] = (short)f2b(sacc[1][e]);
      pfr1[e]     = (short)f2b(sacc[2][e]);
      pfr1[4 + e] = (short)f2b(sacc[3][e]);
    }
    #pragma unroll
    for (int dt = 0; dt < 4; dt++){
      bf16x8 vfr0 = *(bf16x8*)&Vts[half][(dt * 16 + li) * 72 + g * 8];
      bf16x8 vfr1 = *(bf16x8*)&Vts[half][(dt * 16 + li) * 72 + 32 + g * 8];
      oacc[dt] = __builtin_amdgcn_mfma_f32_16x16x32_bf16(vfr0, pfr0, oacc[dt], 0, 0, 0);
      oacc[dt] = __builtin_amdgcn_mfma_f32_16x16x32_bf16(vfr1, pfr1, oacc[dt], 0, 0, 0);
    }
  }

  // merge halves: waves 4-7 publish (m,l,O) via LDS (alias over Ks)
  __syncthreads();
  float* pm = (float*)&Ks[0][0];      // 256 f
  float* pl = pm + 256;               // 256 f
  float* po = pl + 256;               // 4096 f  (total 18432 B = sizeof Ks)
  int slot = qw * 64 + lane;
  if (half == 1){
    pm[slot] = mrun;
    pl[slot] = lrun;
    #pragma unroll
    for (int dt = 0; dt < 4; dt++) *(f32x4*)&po[slot * 16 + dt * 4] = oacc[dt];
  }
  __syncthreads();
  if (half == 0){
    float mb = pm[slot], lb = pl[slot];
    float mm = fmaxf(mrun, mb);
    float ea = __expf(mrun - mm), eb = __expf(mb - mm);
    float linv = 1.0f / (lrun * ea + lb * eb);
    int b = bh >> 3, h = bh & 7;
    u16* op = attnB + (((size_t)(b * 1024 + q0 + qw * 16 + li)) << 9) + h * 64 + g * 4;
    #pragma unroll
    for (int dt = 0; dt < 4; dt++){
      f32x4 ob = *(f32x4*)&po[slot * 16 + dt * 4];
      us4 pk;
      #pragma unroll
      for (int j = 0; j < 4; j++) pk[j] = f2b((oacc[dt][j] * ea + ob[j] * eb) * linv);
      *(us4*)(op + dt * 16) = pk;
    }
  }
}

// ------------------------------------------------------------------
// 10) LN over C + transpose to (B,C,N)
// ------------------------------------------------------------------
__global__ __launch_bounds__(256) void k_ln(const u16* __restrict__ xfB, const float* __restrict__ attnO,
    const float* __restrict__ gamma, const float* __restrict__ beta, float* __restrict__ out){
  __shared__ float mu_s[64], rs_s[64];
  __shared__ float tile[64][65];
  int b = blockIdx.x >> 4, n0 = (blockIdx.x & 15) << 6;
  int t = threadIdx.x, w = t >> 6, lane = t & 63;

  for (int r = w * 16; r < w * 16 + 16; r++){
    size_t rb = ((size_t)(b * 1024 + n0 + r)) << 9;
    const float* ap = attnO + rb + lane * 8;
    const u16*  xp = xfB + rb + lane * 8;
    float4 a0 = *(const float4*)ap;
    float4 a1 = *(const float4*)(ap + 4);
    union { uint4 v; u16 u[8]; } xv; xv.v = *(const uint4*)xp;
    float v0 = a0.x + b2f(xv.u[0]), v1 = a0.y + b2f(xv.u[1]);
    float v2 = a0.z + b2f(xv.u[2]), v3 = a0.w + b2f(xv.u[3]);
    float v4 = a1.x + b2f(xv.u[4]), v5 = a1.y + b2f(xv.u[5]);
    float v6 = a1.z + b2f(xv.u[6]), v7 = a1.w + b2f(xv.u[7]);
    float s  = v0 + v1 + v2 + v3 + v4 + v5 + v6 + v7;
    float s2 = v0*v0 + v1*v1 + v2*v2 + v3*v3 + v4*v4 + v5*v5 + v6*v6 + v7*v7;
    #pragma unroll
    for (int o = 32; o > 0; o >>= 1){ s += __shfl_xor(s, o, 64); s2 += __shfl_xor(s2, o, 64); }
    if (lane == 0){
      float mu = s * (1.0f / 512.0f);
      float var = s2 * (1.0f / 512.0f) - mu * mu;
      mu_s[r] = mu;
      rs_s[r] = 1.0f / sqrtf(var + 1e-5f);
    }
  }
  __syncthreads();

  for (int ch = 0; ch < 8; ch++){
    int c0 = ch * 64;
    {
      int r = t >> 2, cp = (t & 3) << 4;
      size_t rb = (((size_t)(b * 1024 + n0 + r)) << 9) + c0 + cp;
      float mu = mu_s[r], rstd = rs_s[r];
      #pragma unroll
      for (int i2 = 0; i2 < 2; i2++){
        float4 a0 = *(const float4*)(attnO + rb + i2 * 8);
        float4 a1 = *(const float4*)(attnO + rb + i2 * 8 + 4);
        union { uint4 v; u16 u[8]; } xv; xv.v = *(const uint4*)(xfB + rb + i2 * 8);
        float vv[8] = { a0.x + b2f(xv.u[0]), a0.y + b2f(xv.u[1]), a0.z + b2f(xv.u[2]), a0.w + b2f(xv.u[3]),
                        a1.x + b2f(xv.u[4]), a1.y + b2f(xv.u[5]), a1.z + b2f(xv.u[6]), a1.w + b2f(xv.u[7]) };
        #pragma unroll
        for (int i = 0; i < 8; i++){
          int c = c0 + cp + i2 * 8 + i;
          tile[r][cp + i2 * 8 + i] = (vv[i] - mu) * rstd * gamma[c] + beta[c];
        }
      }
    }
    __syncthreads();
    {
      int cl = t >> 2, np_ = (t & 3) << 4;
      float* op = out + (((size_t)(b * 512 + c0 + cl)) << 10) + n0 + np_;
      #pragma unroll
      for (int i = 0; i < 16; i += 4){
        float4 vo = { tile[np_ + i][cl], tile[np_ + i + 1][cl], tile[np_ + i + 2][cl], tile[np_ + i + 3][cl] };
        *(float4*)(op + i) = vo;
      }
    }
    __syncthreads();
  }
}

// ------------------------------------------------------------------
extern "C" void kernel_launch(void* const* d_in, const int* in_sizes, int n_in,
                              void* d_out, int out_size, void* d_ws, size_t ws_size,
                              hipStream_t stream){
  (void)in_sizes; (void)n_in; (void)out_size; (void)ws_size;
  const float* x    = (const float*)d_in[0];
  const float* Wq   = (const float*)d_in[1];
  const float* bq   = (const float*)d_in[2];
  const float* Wk   = (const float*)d_in[3];
  const float* bk   = (const float*)d_in[4];
  const float* Wv   = (const float*)d_in[5];
  const float* bv   = (const float*)d_in[6];
  const float* Wo   = (const float*)d_in[7];
  const float* bo   = (const float*)d_in[8];
  const float* Wsp  = (const float*)d_in[9];
  const float* bsp  = (const float*)d_in[10];
  const float* Wse1 = (const float*)d_in[11];
  const float* bse1 = (const float*)d_in[12];
  const float* Wse2 = (const float*)d_in[13];
  const float* bse2 = (const float*)d_in[14];
  const float* gamma= (const float*)d_in[15];
  const float* beta = (const float*)d_in[16];
  float* out = (float*)d_out;

  char* ws = (char*)d_ws;
  size_t off = 0;
  auto alloc = [&](size_t bytes) -> void* {
    void* p = ws + off;
    off += (bytes + 255) & ~(size_t)255;
    return p;
  };
  u16*   WB     = (u16*)  alloc(1536 * 512 * 2);
  u16*   WoB    = (u16*)  alloc(512 * 512 * 2);
  float* pooled = (float*)alloc(4096 * 4);
  float* cw     = (float*)alloc(4096 * 4);
  float* mbuf   = (float*)alloc(65536 * 4);
  float* bneg   = (float*)alloc(65536 * 4);
  u16*   xfB    = (u16*)  alloc((size_t)8192 * 512 * 2);
  u16*   Qb     = (u16*)  alloc(8388608);
  u16*   Kb     = (u16*)  alloc(8388608);
  u16*   VtG    = (u16*)  alloc(8388608);
  u16*   attnB  = (u16*)  alloc(8388608);
  float* attnO  = (float*)Qb;   // alias Q+K after flash

  k_cvt   <<<dim3(1024), dim3(256), 0, stream>>>(Wq, Wk, Wv, Wo, WB, WoB);
  k_pooled<<<dim3(1024), dim3(256), 0, stream>>>(x, pooled);
  k_se    <<<dim3(8),    dim3(256), 0, stream>>>(pooled, Wse1, bse1, Wse2, bse2, cw);
  k_sp    <<<dim3(128),  dim3(256), 0, stream>>>(x, Wsp, bsp, mbuf);
  k_mask  <<<dim3(64),   dim3(64),  0, stream>>>(mbuf, bneg);
  k_xf    <<<dim3(1024), dim3(256), 0, stream>>>(x, cw, xfB);
  k_gemm<0><<<dim3(64, 12), dim3(256), 0, stream>>>(xfB, WB, bq, bk, bv, Qb, Kb, VtG, (float*)nullptr);
  k_flash <<<dim3(1024), dim3(512), 0, stream>>>(Qb, Kb, VtG, bneg, attnB);
  k_gemm<1><<<dim3(64, 4), dim3(256), 0, stream>>>(attnB, WoB, bo, bo, bo, nullptr, nullptr, nullptr, attnO);
  k_ln    <<<dim3(128),  dim3(256), 0, stream>>>(xfB, attnO, gamma, beta, out);
}